// Round 7
// baseline (432.199 us; speedup 1.0000x reference)
//
#include <hip/hip_runtime.h>

typedef _Float16 f16x8 __attribute__((ext_vector_type(8)));
typedef _Float16 f16x4 __attribute__((ext_vector_type(4)));
typedef float    f32x4 __attribute__((ext_vector_type(4)));

#define Bq   32
#define Lq   4096
#define Eq   1024
#define RO   2049                  // rows_out = cache_len + 1
#define SPANC (Lq - RO)            // 2047
#define NTILE 4098                 // 16-row gemm tiles  (32*2049/16)
#define NCGRP 4094                 // 16-row copy groups (32*2047/16)
#define NB    1024                 // blocks (4 per CU)
#define NITER 5                    // ceil(NTILE/NB)

#define LGKM_BARRIER() asm volatile("s_waitcnt lgkmcnt(0)\n\ts_barrier" ::: "memory")

// ---------------------------------------------------------------------------
// K1: vec[b][e] = inputA[b].W1a[e] + b1a[e] + inputB[b].W1b[e] + b1b[e]
// Wave per e; W rows in registers, loop over b (inputs L1/L2-resident).
// ---------------------------------------------------------------------------
__global__ __launch_bounds__(256) void vec_kernel(
    const float* __restrict__ inA, const float* __restrict__ inB,
    const float* __restrict__ W1a, const float* __restrict__ b1a,
    const float* __restrict__ W1b, const float* __restrict__ b1b,
    float* __restrict__ vec)
{
    int e    = (blockIdx.x * 256 + threadIdx.x) >> 6;
    int lane = threadIdx.x & 63;
    if (e >= Eq) return;

    const float4* wa4 = (const float4*)(W1a + (size_t)e * Eq);
    const float4* wb4 = (const float4*)(W1b + (size_t)e * Eq);
    float4 wa[4], wb[4];
#pragma unroll
    for (int j = 0; j < 4; ++j) { wa[j] = wa4[lane + 64 * j]; wb[j] = wb4[lane + 64 * j]; }
    float bias = b1a[e] + b1b[e];

#pragma unroll 4
    for (int b = 0; b < Bq; ++b) {
        const float4* a4  = (const float4*)(inA + (size_t)b * Eq);
        const float4* bb4 = (const float4*)(inB + (size_t)b * Eq);
        float acc = 0.f;
#pragma unroll
        for (int j = 0; j < 4; ++j) {
            float4 a = a4[lane + 64 * j];
            acc += wa[j].x * a.x + wa[j].y * a.y + wa[j].z * a.z + wa[j].w * a.w;
            float4 v = bb4[lane + 64 * j];
            acc += wb[j].x * v.x + wb[j].y * v.y + wb[j].z * v.z + wb[j].w * v.w;
        }
#pragma unroll
        for (int s = 32; s; s >>= 1) acc += __shfl_xor(acc, s, 64);
        if (lane == 0) vec[(size_t)b * Eq + e] = acc + bias;
    }
}

// ---------------------------------------------------------------------------
// K2: mega kernel — ALL copy + ALL GEMM in one dispatch.
// 1024 blocks x 256 threads (4 waves), 32 KB LDS -> 4 independent blocks/CU.
// Wave w owns N-tile w (out cols 16w..16w+16) with its FULL-K W2 slice in
// 128 VGPRs (32 f16x8 frags) => no cross-wave reduce, no part buffer.
// Per iteration, block handles:
//   gemm tile (16 rows t<=2048): coalesced 1KB-wave loads -> f32 copy-store
//     to ncache -> f16 LDS write in FRAGMENT order (MFMA A-reads are then
//     lane-contiguous conflict-free 16B cells)
//   copy group (16 rows t>2048): pure 1KB-wave load/store stream
// Two lgkm-only barriers couple only 4 waves; global stores never block
// loads (in-order vmcnt: loads of an iteration always precede its stores);
// 4 independent blocks/CU keep HBM saturated through barrier stalls.
// ---------------------------------------------------------------------------
__global__ __launch_bounds__(256, 4) void mega_kernel(
    const float* __restrict__ cache, const float* __restrict__ vec,
    const float* __restrict__ W2, const float* __restrict__ b2,
    float* __restrict__ outp, float* __restrict__ ncache)
{
    __shared__ _Float16 rowbuf[16384];   // 32 KB: frag cell (s,l) = 16B at (s*64+l)*16
    char* rbb = (char*)rowbuf;

    const int l  = threadIdx.x & 63, w = threadIdx.x >> 6;  // lane, wave(=N-tile)
    const int m  = l & 15;          // A/B frag row | D col
    const int hk = l >> 4;          // k-subgroup
    const int r  = 4 * w + hk;      // staging row 0..15
    const int cl = m;               // staging col-lane 0..15

    // B fragments (once): bfr[s] = W2[16w+m][s*32 + hk*8 .. +8] as f16
    f16x8 bfr[32];
    {
        const float* wrow = W2 + (size_t)(16 * w + m) * Eq + hk * 8;
#pragma unroll
        for (int s = 0; s < 32; ++s) {
            float4 x = *(const float4*)(wrow + s * 32);
            float4 y = *(const float4*)(wrow + s * 32 + 4);
            f16x8 h;
            h[0] = (_Float16)x.x; h[1] = (_Float16)x.y;
            h[2] = (_Float16)x.z; h[3] = (_Float16)x.w;
            h[4] = (_Float16)y.x; h[5] = (_Float16)y.y;
            h[6] = (_Float16)y.z; h[7] = (_Float16)y.w;
            bfr[s] = h;
        }
    }
    const float bias = b2[16 * w + m];

    int tile = blockIdx.x;
#pragma unroll 1
    for (int it = 0; it < NITER; ++it, tile += NB) {
        const bool g_ok = (tile < NTILE);

        // ---- stage gemm tile: load 16 f4 -> copy-store f32 -> f16 LDS ----
        if (g_ok) {
            int R = tile * 16 + r, bb = R / RO, t = R - bb * RO;
            const float* src = (t == RO - 1) ? (vec + (size_t)bb * Eq)
                                             : (cache + ((size_t)bb * Lq + t) * Eq);
            float* dst = ncache + ((size_t)bb * Lq + t) * Eq;
            float4 gx[16];
#pragma unroll
            for (int j = 0; j < 16; ++j) gx[j] = *(const float4*)(src + 4 * (cl + 16 * j));
#pragma unroll
            for (int j = 0; j < 16; ++j) *(float4*)(dst + 4 * (cl + 16 * j)) = gx[j];
#pragma unroll
            for (int j = 0; j < 16; ++j) {
                int c = cl + 16 * j;               // f4 index in row
                int s = c >> 3, kq = (c & 7) >> 1, e = c & 1;
                f16x4 h;
                h[0] = (_Float16)gx[j].x; h[1] = (_Float16)gx[j].y;
                h[2] = (_Float16)gx[j].z; h[3] = (_Float16)gx[j].w;
                *(f16x4*)(rbb + ((s * 64 + kq * 16 + r) * 16 + e * 8)) = h;
            }
        }

        // ---- copy group: pure stream ----
        if (tile < NCGRP) {
            int C = tile * 16 + r, cb = C / SPANC, tc = RO + C - cb * SPANC;
            const float4* s4 = (const float4*)(cache + ((size_t)cb * Lq + tc) * Eq);
            float4* d4 = (float4*)(ncache + ((size_t)cb * Lq + tc) * Eq);
            float4 cx[16];
#pragma unroll
            for (int j = 0; j < 16; ++j) cx[j] = s4[cl + 16 * j];
#pragma unroll
            for (int j = 0; j < 16; ++j) d4[cl + 16 * j] = cx[j];
        }

        LGKM_BARRIER();   // rowbuf ready (LDS only; global ops stay in flight)

        // ---- MFMA: full K per wave, A-frags conflict-free from LDS ----
        if (g_ok) {
            f32x4 acc = {0.f, 0.f, 0.f, 0.f};
#pragma unroll
            for (int s = 0; s < 32; ++s) {
                f16x8 a = *(const f16x8*)(rbb + (s * 64 + l) * 16);
                acc = __builtin_amdgcn_mfma_f32_16x16x32_f16(a, bfr[s], acc, 0, 0, 0);
            }
            int R0 = tile * 16 + hk * 4;           // D row = hk*4 + ri, col = 16w+m
#pragma unroll
            for (int ri = 0; ri < 4; ++ri)
                outp[(size_t)(R0 + ri) * 64 + 16 * w + m] = acc[ri] + bias;
        }

        LGKM_BARRIER();   // rowbuf WAR: reads(i) done before writes(i+1)
    }
}

// ---------------------------------------------------------------------------
extern "C" void kernel_launch(void* const* d_in, const int* in_sizes, int n_in,
                              void* d_out, int out_size, void* d_ws, size_t ws_size,
                              hipStream_t stream)
{
    const float* inA   = (const float*)d_in[0];
    const float* inB   = (const float*)d_in[1];
    const float* cache = (const float*)d_in[2];
    const float* W1a   = (const float*)d_in[3];
    const float* b1a   = (const float*)d_in[4];
    const float* W1b   = (const float*)d_in[5];
    const float* b1b   = (const float*)d_in[6];
    const float* W2    = (const float*)d_in[7];
    const float* b2v   = (const float*)d_in[8];

    float* outp   = (float*)d_out;                   // (B,2049,64) then (B,L,E)
    float* ncache = outp + (size_t)Bq * RO * 64;
    float* vecbuf = (float*)d_ws;                    // 32*1024 f32

    vec_kernel<<<dim3(256), dim3(256), 0, stream>>>(inA, inB, W1a, b1a, W1b, b1b, vecbuf);

    mega_kernel<<<dim3(NB), dim3(256), 0, stream>>>(cache, vecbuf, W2, b2v,
                                                    outp, ncache);
}

// Round 8
// 407.131 us; speedup vs baseline: 1.0616x; 1.0616x over previous
//
#include <hip/hip_runtime.h>

typedef _Float16 f16x8 __attribute__((ext_vector_type(8)));
typedef _Float16 f16x4 __attribute__((ext_vector_type(4)));
typedef float    f32x4 __attribute__((ext_vector_type(4)));

#define Bq   32
#define Lq   4096
#define Eq   1024
#define RO   2049                  // rows_out = cache_len + 1
#define NTILE 4098                 // 16-row gemm tiles (32*2049/16)

// ---------------------------------------------------------------------------
// K1: vec[b][e] = inputA[b].W1a[e] + b1a[e] + inputB[b].W1b[e] + b1b[e]
// ---------------------------------------------------------------------------
__global__ __launch_bounds__(256) void vec_kernel(
    const float* __restrict__ inA, const float* __restrict__ inB,
    const float* __restrict__ W1a, const float* __restrict__ b1a,
    const float* __restrict__ W1b, const float* __restrict__ b1b,
    float* __restrict__ vec)
{
    int e    = (blockIdx.x * 256 + threadIdx.x) >> 6;
    int lane = threadIdx.x & 63;
    if (e >= Eq) return;

    const float4* wa4 = (const float4*)(W1a + (size_t)e * Eq);
    const float4* wb4 = (const float4*)(W1b + (size_t)e * Eq);
    float4 wa[4], wb[4];
#pragma unroll
    for (int j = 0; j < 4; ++j) { wa[j] = wa4[lane + 64 * j]; wb[j] = wb4[lane + 64 * j]; }
    float bias = b1a[e] + b1b[e];

#pragma unroll 4
    for (int b = 0; b < Bq; ++b) {
        const float4* a4  = (const float4*)(inA + (size_t)b * Eq);
        const float4* bb4 = (const float4*)(inB + (size_t)b * Eq);
        float acc = 0.f;
#pragma unroll
        for (int j = 0; j < 4; ++j) {
            float4 a = a4[lane + 64 * j];
            acc += wa[j].x * a.x + wa[j].y * a.y + wa[j].z * a.z + wa[j].w * a.w;
            float4 v = bb4[lane + 64 * j];
            acc += wb[j].x * v.x + wb[j].y * v.y + wb[j].z * v.z + wb[j].w * v.w;
        }
#pragma unroll
        for (int s = 32; s; s >>= 1) acc += __shfl_xor(acc, s, 64);
        if (lane == 0) vec[(size_t)b * Eq + e] = acc + bias;
    }
}

// ---------------------------------------------------------------------------
// K2: pure streaming copy of rows t in [RO, L)  (proven ~6.5 TB/s shape).
// ---------------------------------------------------------------------------
__global__ __launch_bounds__(256) void copy_kernel(
    const float* __restrict__ src, float* __restrict__ dst, int f4_per_b)
{
    int b = blockIdx.y;
    int base = blockIdx.x * 1024 + threadIdx.x;
    size_t rowbase = ((size_t)b * Lq + RO) * (Eq / 4);
    const float4* s4 = (const float4*)src;
    float4* d4 = (float4*)dst;
#pragma unroll
    for (int j = 0; j < 4; ++j) {
        int r4 = base + j * 256;
        if (r4 < f4_per_b) d4[rowbase + r4] = s4[rowbase + r4];
    }
}

// ---------------------------------------------------------------------------
// K3: wave-private fused copy+GEMM. 256 blocks x 1024 threads (16 waves),
// 144 KB LDS (1 block/CU, 4 waves/SIMD). ZERO barriers in the hot loop.
//   - W2 staged once into LDS, f16, exact B-fragment order (one __syncthreads)
//   - each wave owns a 16-row tile; per K-chunk (32 feats):
//       load 8rowsx128B x2  ->  copy-store f32 -> cvt f16 -> ds_write into
//       the wave's PRIVATE 1KB frag-ordered buffer -> conflict-free
//       ds_read_b128 A-frag + 4 B-frag reads -> 4 MFMA (acc 16 f32)
//   - loads for chunk kc+2 issued 2 chunks ahead (reg double-buffer in
//     NAMED float4s; ~65 VGPR total, cap 128 => no spill)
// Load balance: blocks 0,1 take 17 tiles (wave 0 loops twice), rest 16.
// ---------------------------------------------------------------------------
__global__ __launch_bounds__(1024, 4) void mm_kernel(
    const float* __restrict__ cache, const float* __restrict__ vec,
    const float* __restrict__ W2, const float* __restrict__ b2,
    float* __restrict__ outp, float* __restrict__ ncache)
{
    __shared__ _Float16 w2lds[64 * Eq];    // 128 KB, B-frag order
    __shared__ _Float16 abuf[16 * 512];    // 16 KB: per-wave 1 KB chunk buffers

    const int tid = threadIdx.x;
    const int w = tid >> 6, l = tid & 63;

    // ---- stage W2 -> LDS: frag(nt,ks) cell for lane l at ((nt*32+ks)*64+l)*16,
    //      holding W2[16nt+(l&15)][ks*32+(l>>4)*8 + j], j=0..7 (f16) ----
    {
        int nt  = w >> 2;
        int ks0 = (w & 3) * 8;
        const float* wrow = W2 + (size_t)(16 * nt + (l & 15)) * Eq + ((l >> 4) * 8);
#pragma unroll
        for (int s = 0; s < 8; ++s) {
            int ks = ks0 + s;
            float4 x = *(const float4*)(wrow + ks * 32);
            float4 y = *(const float4*)(wrow + ks * 32 + 4);
            f16x8 h;
            h[0] = (_Float16)x.x; h[1] = (_Float16)x.y;
            h[2] = (_Float16)x.z; h[3] = (_Float16)x.w;
            h[4] = (_Float16)y.x; h[5] = (_Float16)y.y;
            h[6] = (_Float16)y.z; h[7] = (_Float16)y.w;
            *(f16x8*)((char*)w2lds + (size_t)((nt * 32 + ks) * 64 + l) * 16) = h;
        }
    }
    __syncthreads();   // the ONLY block-wide barrier

    const float bias0 = b2[l & 15],        bias1 = b2[16 + (l & 15)];
    const float bias2 = b2[32 + (l & 15)], bias3 = b2[48 + (l & 15)];

    // wave-private chunk buffer addresses
    char* myw = (char*)abuf + w * 1024;
    // writer lane l holds rows (l>>3) and (l>>3)+8, feats 4*(l&7)..+4:
    // dest cell lambda = row + 16*kg, kg=(l>>1)&3; byte = lambda*16 + (l&1)*8
    char* wA = myw + (((l >> 3) + 16 * ((l >> 1) & 3)) * 16 + (l & 1) * 8);
    char* wB = wA + 128;                                  // row+8 => +8 cells
    const f16x8* aread = (const f16x8*)(myw + l * 16);    // contiguous, conflict-free
    const char* bb0 = (char*)w2lds + l * 16;              // + nt*32768 + kc*1024

    const int cnt  = (blockIdx.x < 2) ? 17 : 16;
    const int strt = blockIdx.x * 16 + ((blockIdx.x < 2) ? blockIdx.x : 2);

    for (int ti = w; ti < cnt; ti += 16) {
        const int tile = strt + ti;
        const int RA = tile * 16 + (l >> 3), RB = RA + 8;
        const int bbA = RA / RO, tA = RA - bbA * RO;
        const int bbB = RB / RO, tB = RB - bbB * RO;
        const float* srcA = ((tA == RO - 1) ? (vec + (size_t)bbA * Eq)
                                            : (cache + ((size_t)bbA * Lq + tA) * Eq)) + 4 * (l & 7);
        const float* srcB = ((tB == RO - 1) ? (vec + (size_t)bbB * Eq)
                                            : (cache + ((size_t)bbB * Lq + tB) * Eq)) + 4 * (l & 7);
        float* dstA = ncache + ((size_t)bbA * Lq + tA) * Eq + 4 * (l & 7);
        float* dstB = ncache + ((size_t)bbB * Lq + tB) * Eq + 4 * (l & 7);

        f32x4 acc0 = {0.f,0.f,0.f,0.f}, acc1 = acc0, acc2 = acc0, acc3 = acc0;

        float4 e0 = *(const float4*)(srcA);        // chunk 0 in flight
        float4 e1 = *(const float4*)(srcB);
        float4 o0 = *(const float4*)(srcA + 32);   // chunk 1 in flight
        float4 o1 = *(const float4*)(srcB + 32);

#pragma unroll
        for (int kc = 0; kc < 32; kc += 2) {
            // ---- chunk kc (E regs) ----
            *(float4*)(dstA + kc * 32) = e0;               // fused copy
            *(float4*)(dstB + kc * 32) = e1;
            {
                f16x4 hA, hB;
                hA[0]=(_Float16)e0.x; hA[1]=(_Float16)e0.y; hA[2]=(_Float16)e0.z; hA[3]=(_Float16)e0.w;
                hB[0]=(_Float16)e1.x; hB[1]=(_Float16)e1.y; hB[2]=(_Float16)e1.z; hB[3]=(_Float16)e1.w;
                *(f16x4*)wA = hA;
                *(f16x4*)wB = hB;
            }
            {   // prefetch chunk kc+2 (clamped; wrap reads are L2-hot)
                int kn = (kc + 2) & 31;
                e0 = *(const float4*)(srcA + kn * 32);
                e1 = *(const float4*)(srcB + kn * 32);
            }
            {
                f16x8 a = *aread;   // compiler inserts lgkm wait after ds_writes
                acc0 = __builtin_amdgcn_mfma_f32_16x16x32_f16(a, *(const f16x8*)(bb0 + 0 * 32768 + kc * 1024), acc0, 0, 0, 0);
                acc1 = __builtin_amdgcn_mfma_f32_16x16x32_f16(a, *(const f16x8*)(bb0 + 1 * 32768 + kc * 1024), acc1, 0, 0, 0);
                acc2 = __builtin_amdgcn_mfma_f32_16x16x32_f16(a, *(const f16x8*)(bb0 + 2 * 32768 + kc * 1024), acc2, 0, 0, 0);
                acc3 = __builtin_amdgcn_mfma_f32_16x16x32_f16(a, *(const f16x8*)(bb0 + 3 * 32768 + kc * 1024), acc3, 0, 0, 0);
            }
            // ---- chunk kc+1 (O regs) ----
            *(float4*)(dstA + (kc + 1) * 32) = o0;
            *(float4*)(dstB + (kc + 1) * 32) = o1;
            {
                f16x4 hA, hB;
                hA[0]=(_Float16)o0.x; hA[1]=(_Float16)o0.y; hA[2]=(_Float16)o0.z; hA[3]=(_Float16)o0.w;
                hB[0]=(_Float16)o1.x; hB[1]=(_Float16)o1.y; hB[2]=(_Float16)o1.z; hB[3]=(_Float16)o1.w;
                *(f16x4*)wA = hA;
                *(f16x4*)wB = hB;
            }
            {
                int kn = (kc + 3) & 31;
                o0 = *(const float4*)(srcA + kn * 32);
                o1 = *(const float4*)(srcB + kn * 32);
            }
            {
                f16x8 a = *aread;
                acc0 = __builtin_amdgcn_mfma_f32_16x16x32_f16(a, *(const f16x8*)(bb0 + 0 * 32768 + (kc + 1) * 1024), acc0, 0, 0, 0);
                acc1 = __builtin_amdgcn_mfma_f32_16x16x32_f16(a, *(const f16x8*)(bb0 + 1 * 32768 + (kc + 1) * 1024), acc1, 0, 0, 0);
                acc2 = __builtin_amdgcn_mfma_f32_16x16x32_f16(a, *(const f16x8*)(bb0 + 2 * 32768 + (kc + 1) * 1024), acc2, 0, 0, 0);
                acc3 = __builtin_amdgcn_mfma_f32_16x16x32_f16(a, *(const f16x8*)(bb0 + 3 * 32768 + (kc + 1) * 1024), acc3, 0, 0, 0);
            }
        }

        // ---- out store: D col = l&15, row = (l>>4)*4 + r ----
        const int mrow = tile * 16 + (l >> 4) * 4;
        const int mcol = l & 15;
#pragma unroll
        for (int r = 0; r < 4; ++r) {
            float* op = outp + (size_t)(mrow + r) * 64 + mcol;
            op[0]  = acc0[r] + bias0;
            op[16] = acc1[r] + bias1;
            op[32] = acc2[r] + bias2;
            op[48] = acc3[r] + bias3;
        }
    }
}

// ---------------------------------------------------------------------------
extern "C" void kernel_launch(void* const* d_in, const int* in_sizes, int n_in,
                              void* d_out, int out_size, void* d_ws, size_t ws_size,
                              hipStream_t stream)
{
    const float* inA   = (const float*)d_in[0];
    const float* inB   = (const float*)d_in[1];
    const float* cache = (const float*)d_in[2];
    const float* W1a   = (const float*)d_in[3];
    const float* b1a   = (const float*)d_in[4];
    const float* W1b   = (const float*)d_in[5];
    const float* b1b   = (const float*)d_in[6];
    const float* W2    = (const float*)d_in[7];
    const float* b2v   = (const float*)d_in[8];

    float* outp   = (float*)d_out;                   // (B,2049,64) then (B,L,E)
    float* ncache = outp + (size_t)Bq * RO * 64;
    float* vecbuf = (float*)d_ws;                    // 32*1024 f32

    vec_kernel<<<dim3(256), dim3(256), 0, stream>>>(inA, inB, W1a, b1a, W1b, b1b, vecbuf);

    // fused copy+GEMM for rows t in [0, 2048]
    mm_kernel<<<dim3(256), dim3(1024), 0, stream>>>(cache, vecbuf, W2, b2v,
                                                    outp, ncache);

    // pure copy of rows t in [2049, 4096)
    int f4_per_b = (Lq - RO) * (Eq / 4);             // 2047*256
    copy_kernel<<<dim3((f4_per_b + 1023) / 1024, Bq), dim3(256), 0, stream>>>(
        cache, ncache, f4_per_b);
}